// Round 20
// baseline (369.403 us; speedup 1.0000x reference)
//
#include <hip/hip_runtime.h>
#include <hip/hip_bf16.h>
#include <cstdint>
#include <cstddef>

#define IN_D 256
#define HID 128
#define OUT_D 64
#define NSLOPE 0.2f
#define SBCAP 20480   // per-super-bucket staging capacity (mean 16.4k, +32 sigma)

typedef __attribute__((ext_vector_type(8))) short bf16x8;
typedef __attribute__((ext_vector_type(4))) float f32x4;
typedef __attribute__((ext_vector_type(8))) unsigned short u16x8;
typedef unsigned short u16;

static inline int cdiv(long long a, long long b) { return (int)((a + b - 1) / b); }

__device__ __forceinline__ float lrelu(float v) { return v >= 0.f ? v : NSLOPE * v; }
__device__ __forceinline__ int imin(int a, int b) { return a < b ? a : b; }

// f32 -> bf16 (RNE) via bit ops
__device__ __forceinline__ u16 f2bf(float f) {
  unsigned u = __float_as_uint(f);
  return (u16)((u + 0x7FFFu + ((u >> 16) & 1u)) >> 16);
}
__device__ __forceinline__ float bf2f(u16 h) {
  return __uint_as_float((unsigned)h << 16);
}

// ---------------- Weight prep (W1 + W2, one launch) -------------------------
__global__ void k_prep(const float* __restrict__ W1, u16* __restrict__ WThi,
                       u16* __restrict__ WTlo, const float* __restrict__ W2,
                       u16* __restrict__ W2Thi, u16* __restrict__ W2Tlo) {
  int idx = blockIdx.x * 256 + threadIdx.x;
  if (idx < IN_D * IN_D) {
    int k = idx >> 8, n = idx & 255;
    float f = W1[idx];
    u16 h = f2bf(f);
    WThi[n * IN_D + k] = h;
    WTlo[n * IN_D + k] = f2bf(f - bf2f(h));
  }
  int idx2 = idx - IN_D * IN_D;
  if (idx2 >= 0 && idx2 < HID * OUT_D) {
    int k = idx2 >> 6, n = idx2 & 63;
    float f = W2[idx2];
    u16 h = f2bf(f);
    W2Thi[n * HID + k] = h;
    W2Tlo[n * HID + k] = f2bf(f - bf2f(h));
  }
}

// ---------------- FUSED: gemm1 || sort pass 1 -------------------------------
// gemm1 (even-ish blocks): BM=128, 8 waves, LDS-staged split-bf16 B (padded).
// sort1 (odd-ish blocks): 2048 edges -> super-buckets (dst>>10) via LDS hist,
// ONE returning global atomic per (block,bin), LDS-returning ranks. sort1's
// tiny counter arrays overlay the gemm branch's LDS (cast), so LDS = 40KB.
__launch_bounds__(512)
__global__ void k_gemm1sort(const float* __restrict__ x, const u16* __restrict__ WThi,
                            const u16* __restrict__ WTlo,
                            const float* __restrict__ as1, const float* __restrict__ ad1,
                            u16* __restrict__ hb, float* __restrict__ a_s,
                            float* __restrict__ a_d, int N,
                            const int* __restrict__ ei, int E,
                            int* __restrict__ sbCount, int2* __restrict__ st1,
                            int G1, int G2) {
  __shared__ u16 ldsb[2][10240];  // 40KB (gemm branch); sort1 overlays ints
  int bid = blockIdx.x;
  int m2 = (G1 < G2 ? G1 : G2) * 2;
  int type, tb;
  if (bid < m2) { type = bid & 1; tb = bid >> 1; }
  else { int ex = bid - m2; type = (G1 > G2) ? 0 : 1; tb = m2 / 2 + ex; }
  int tid = threadIdx.x;

  if (type == 1) {
    // ---- sort1: 4 edges/thread (512 thr -> 2048 edges/block) ----
    int* hist = (int*)&ldsb[0][0];
    int* gb   = hist + 128;
    int* cur  = hist + 256;
    if (tid < 128) hist[tid] = 0;
    __syncthreads();
    int base = tb * 2048 + tid;
    int sv[4], dv[4]; bool vv[4];
    #pragma unroll
    for (int q = 0; q < 4; ++q) {
      int i = base + q * 512;
      vv[q] = i < E;
      int ic = vv[q] ? i : 0;
      sv[q] = ei[ic];
      dv[q] = ei[E + ic];
    }
    #pragma unroll
    for (int q = 0; q < 4; ++q)
      if (vv[q]) atomicAdd(&hist[dv[q] >> 10], 1);   // LDS, non-returning
    __syncthreads();
    if (tid < 128) {
      int h = hist[tid];
      gb[tid] = h ? atomicAdd(&sbCount[tid], h) : 0; // ONE returning atomic/bin
      cur[tid] = 0;
    }
    __syncthreads();
    #pragma unroll
    for (int q = 0; q < 4; ++q)
      if (vv[q]) {
        int sb = dv[q] >> 10;
        int r = atomicAdd(&cur[sb], 1);              // LDS returning (fast)
        int slot = gb[sb] + r;
        if (slot < SBCAP) st1[(size_t)sb * SBCAP + slot] = make_int2(sv[q], dv[q]);
      }
    return;
  }

  // ---- gemm1 (split-bf16 MFMA, LDS-staged B) ----
  int w = tid >> 6, l = tid & 63;
  int l15 = l & 15, l4 = l >> 4;
  int rowbase = tb * 128 + w * 16;
  int row = rowbase + l15;
  int rowc = (row < N) ? row : (N - 1);
  const float* xp = x + (size_t)rowc * IN_D + l4 * 8;

  f32x4 acc[16];
  #pragma unroll
  for (int t = 0; t < 16; ++t) acc[t] = (f32x4){0.f, 0.f, 0.f, 0.f};

  const int ridx = (l15 * 5 + l4) * 8;   // padded rows: + t*640 per tile

  for (int kk = 0; kk < 8; ++kk) {
    __syncthreads();
    #pragma unroll
    for (int it = 0; it < 2; ++it) {
      int c = tid + it * 512;
      int n = c >> 2, ch = c & 3;
      size_t soff = (size_t)n * IN_D + kk * 32 + ch * 8;
      uint4 vh = *(const uint4*)(WThi + soff);
      uint4 vl = *(const uint4*)(WTlo + soff);
      int dsl = (n * 5 + ch) * 8;
      *(uint4*)&ldsb[0][dsl] = vh;
      *(uint4*)&ldsb[1][dsl] = vl;
    }
    __syncthreads();

    f32x4 v0 = *(const f32x4*)(xp + kk * 32);
    f32x4 v1 = *(const f32x4*)(xp + kk * 32 + 4);
    bf16x8 ah, al;
    #pragma unroll
    for (int j = 0; j < 4; ++j) {
      u16 h0 = f2bf(v0[j]);
      ah[j] = (short)h0; al[j] = (short)f2bf(v0[j] - bf2f(h0));
      u16 h1 = f2bf(v1[j]);
      ah[j + 4] = (short)h1; al[j + 4] = (short)f2bf(v1[j] - bf2f(h1));
    }
    #pragma unroll
    for (int t = 0; t < 16; ++t) {
      bf16x8 bh = *(const bf16x8*)&ldsb[0][ridx + t * 640];
      bf16x8 bl = *(const bf16x8*)&ldsb[1][ridx + t * 640];
      acc[t] = __builtin_amdgcn_mfma_f32_16x16x32_bf16(ah, bh, acc[t], 0, 0, 0);
      acc[t] = __builtin_amdgcn_mfma_f32_16x16x32_bf16(al, bh, acc[t], 0, 0, 0);
      acc[t] = __builtin_amdgcn_mfma_f32_16x16x32_bf16(ah, bl, acc[t], 0, 0, 0);
    }
  }

  #pragma unroll
  for (int r = 0; r < 4; ++r) {
    int rr = rowbase + l4 * 4 + r;
    if (rr < N) {
      u16* hp = hb + (size_t)rr * IN_D + l15;
      #pragma unroll
      for (int t = 0; t < 16; ++t) hp[t * 16] = f2bf(acc[t][r]);
    }
  }
  float asv[16], adv[16];
  #pragma unroll
  for (int t = 0; t < 16; ++t) { asv[t] = as1[t * 16 + l15]; adv[t] = ad1[t * 16 + l15]; }
  float ps0[4] = {}, ps1[4] = {}, pd0[4] = {}, pd1[4] = {};
  #pragma unroll
  for (int t = 0; t < 16; ++t) {
    #pragma unroll
    for (int r = 0; r < 4; ++r) {
      float v = acc[t][r];
      if (t < 8) { ps0[r] += v * asv[t]; pd0[r] += v * adv[t]; }
      else       { ps1[r] += v * asv[t]; pd1[r] += v * adv[t]; }
    }
  }
  #pragma unroll
  for (int r = 0; r < 4; ++r) {
    #pragma unroll
    for (int o = 1; o < 16; o <<= 1) {
      ps0[r] += __shfl_xor(ps0[r], o); ps1[r] += __shfl_xor(ps1[r], o);
      pd0[r] += __shfl_xor(pd0[r], o); pd1[r] += __shfl_xor(pd1[r], o);
    }
    int rr = rowbase + l4 * 4 + r;
    if (l15 == 0 && rr < N) {
      a_s[rr * 2] = ps0[r]; a_s[rr * 2 + 1] = ps1[r];
      a_d[rr * 2] = pd0[r]; a_d[rr * 2 + 1] = pd1[r];
    }
  }
}

// ---------------- Sort pass 2: super-bucket -> per-node CSR (ro/col) --------
__launch_bounds__(256)
__global__ void k_sort2(const int* __restrict__ sbCount, const int2* __restrict__ st1,
                        int* __restrict__ ro, int* __restrict__ col, int N) {
  __shared__ int hist2[1024], pref[1024], cur[1024];
  __shared__ int sc[256];
  __shared__ int gbaseS, cntS;
  int tid = threadIdx.x;
  int sb = blockIdx.x;
  int nb0 = sb << 10;
  if (tid == 0) {
    int g = 0;
    for (int b = 0; b < sb; ++b) g += imin(sbCount[b], SBCAP);
    gbaseS = g;
    cntS = imin(sbCount[sb], SBCAP);
  }
  for (int t = tid; t < 1024; t += 256) hist2[t] = 0;
  __syncthreads();
  int gbase = gbaseS, cnt = cntS;
  const int2* sp = st1 + (size_t)sb * SBCAP;
  for (int j = tid; j < cnt; j += 256) atomicAdd(&hist2[sp[j].y - nb0], 1);
  __syncthreads();
  int a0 = hist2[tid * 4], a1 = hist2[tid * 4 + 1],
      a2 = hist2[tid * 4 + 2], a3 = hist2[tid * 4 + 3];
  int s4 = a0 + a1 + a2 + a3;
  sc[tid] = s4; __syncthreads();
  for (int o = 1; o < 256; o <<= 1) {
    int add = (tid >= o) ? sc[tid - o] : 0;
    __syncthreads();
    sc[tid] += add;
    __syncthreads();
  }
  int eb = sc[tid] - s4;
  pref[tid * 4] = eb;
  pref[tid * 4 + 1] = eb + a0;
  pref[tid * 4 + 2] = eb + a0 + a1;
  pref[tid * 4 + 3] = eb + a0 + a1 + a2;
  __syncthreads();
  for (int t = tid; t < 1024; t += 256) {
    cur[t] = pref[t];
    int n = nb0 + t;
    if (n < N) ro[n] = gbase + pref[t];
  }
  if (sb == (int)gridDim.x - 1 && tid == 0) ro[N] = gbase + cnt;
  __syncthreads();
  for (int j = tid; j < cnt; j += 256) {
    int2 e = sp[j];
    int r = atomicAdd(&cur[e.y - nb0], 1);
    col[gbase + r] = e.x;
  }
}

// ---------------- Layer 1 agg + Layer 2 GEMM, fused (flat CSR) --------------
__launch_bounds__(256)
__global__ void k_fagg1g2(const int* __restrict__ ro, const int* __restrict__ col,
                          const float* __restrict__ a_s, const float* __restrict__ a_d,
                          const u16* __restrict__ hb, const float* __restrict__ b1,
                          const u16* __restrict__ W2Thi, const u16* __restrict__ W2Tlo,
                          const float* __restrict__ as2, const float* __restrict__ ad2,
                          u16* __restrict__ h2b, float* __restrict__ a_s2,
                          float* __restrict__ a_d2, int N) {
  __shared__ float rowLds[16][132];
  __shared__ float red[2][16][4];
  int tid = threadIdx.x;
  int wid = tid >> 6, lane = tid & 63;
  int base = blockIdx.x * 16;

  int half = lane >> 5;
  int l5 = lane & 31;
  int head = l5 >> 4;

  for (int rr = 0; rr < 4; ++rr) {
    int ln = wid * 4 + rr;
    int n = base + ln;
    if (n >= N) { if (lane < 16) for (int q = 0; q < 8; ++q) rowLds[ln][lane * 8 + q] = 0.f; continue; }
    int beg = ro[n], end = ro[n + 1];
    float ad0 = a_d[2 * n], ad1 = a_d[2 * n + 1];
    float myAd = head ? ad1 : ad0;

    float sacc = 0.f;
    float accv[8] = {};
    if (half == 0) {   // self-loop
      float2 asn = *(const float2*)&a_s[2 * (size_t)n];
      float wv = __expf(lrelu((head ? asn.y : asn.x) + myAd));
      sacc = wv;
      const u16x8 hv = *(const u16x8*)&hb[(size_t)n * IN_D + l5 * 8];
      #pragma unroll
      for (int q = 0; q < 8; ++q) accv[q] = wv * bf2f(hv[q]);
    }
    #pragma unroll 4
    for (int j = beg; j < end; j += 2) {
      int jj = j + half;
      bool valid = jj < end;
      int sidx = col[valid ? jj : beg];
      float2 asv = *(const float2*)&a_s[2 * (size_t)sidx];
      float e = (head ? asv.y : asv.x) + myAd;
      float wv = __expf(lrelu(e));
      wv = valid ? wv : 0.f;
      sacc += wv;
      const u16x8 hv = *(const u16x8*)&hb[(size_t)sidx * IN_D + l5 * 8];
      #pragma unroll
      for (int q = 0; q < 8; ++q) accv[q] += wv * bf2f(hv[q]);
    }
    sacc += __shfl_xor(sacc, 32);
    float myScale = 0.5f / sacc;
    #pragma unroll
    for (int q = 0; q < 8; ++q) {
      accv[q] *= myScale;
      accv[q] += __shfl_xor(accv[q], 16);
      accv[q] += __shfl_xor(accv[q], 32);
    }
    if (lane < 16) {
      #pragma unroll
      for (int q = 0; q < 8; ++q) rowLds[ln][lane * 8 + q] = accv[q];
    }
  }
  __syncthreads();

  int l15 = lane & 15, l4 = lane >> 4;
  f32x4 acc2 = (f32x4){0.f, 0.f, 0.f, 0.f};
  #pragma unroll
  for (int kk = 0; kk < 4; ++kk) {
    int k0 = kk * 32 + l4 * 8;
    f32x4 bv0 = *(const f32x4*)(b1 + k0);
    f32x4 bv1 = *(const f32x4*)(b1 + k0 + 4);
    bf16x8 ah, al;
    #pragma unroll
    for (int j = 0; j < 4; ++j) {
      float u0 = rowLds[l15][k0 + j] + bv0[j]; u0 = (u0 > 0.f) ? u0 : 0.f;
      u16 h0 = f2bf(u0);
      ah[j] = (short)h0; al[j] = (short)f2bf(u0 - bf2f(h0));
      float u1 = rowLds[l15][k0 + 4 + j] + bv1[j]; u1 = (u1 > 0.f) ? u1 : 0.f;
      u16 h1 = f2bf(u1);
      ah[j + 4] = (short)h1; al[j + 4] = (short)f2bf(u1 - bf2f(h1));
    }
    size_t boff = (size_t)(wid * 16 + l15) * HID + k0;
    bf16x8 bh = *(const bf16x8*)(W2Thi + boff);
    bf16x8 bl = *(const bf16x8*)(W2Tlo + boff);
    acc2 = __builtin_amdgcn_mfma_f32_16x16x32_bf16(ah, bh, acc2, 0, 0, 0);
    acc2 = __builtin_amdgcn_mfma_f32_16x16x32_bf16(al, bh, acc2, 0, 0, 0);
    acc2 = __builtin_amdgcn_mfma_f32_16x16x32_bf16(ah, bl, acc2, 0, 0, 0);
  }

  float asv = as2[wid * 16 + l15], adv = ad2[wid * 16 + l15];
  float ps[4], pd[4];
  #pragma unroll
  for (int r = 0; r < 4; ++r) {
    int n = base + l4 * 4 + r;
    if (n < N) h2b[(size_t)n * OUT_D + wid * 16 + l15] = f2bf(acc2[r]);
    ps[r] = acc2[r] * asv; pd[r] = acc2[r] * adv;
    #pragma unroll
    for (int o = 1; o < 16; o <<= 1) { ps[r] += __shfl_xor(ps[r], o); pd[r] += __shfl_xor(pd[r], o); }
    if (l15 == 0) { red[0][l4 * 4 + r][wid] = ps[r]; red[1][l4 * 4 + r][wid] = pd[r]; }
  }
  __syncthreads();
  if (tid < 32) {
    int ln = tid >> 1, kind = tid & 1;
    int n = base + ln;
    if (n < N) {
      float v = red[kind][ln][0] + red[kind][ln][1] + red[kind][ln][2] + red[kind][ln][3];
      if (kind == 0) a_s2[n] = v; else a_d2[n] = v;
    }
  }
}

// ---------------- Layer 2: single-pass edge pipeline + bias (flat CSR) ------
__launch_bounds__(256)
__global__ void k_fagg2(const int* __restrict__ ro, const int* __restrict__ col,
                        const float* __restrict__ a_s, const float* __restrict__ a_d,
                        const u16* __restrict__ h2b, const float* __restrict__ b2,
                        float* __restrict__ out, int N) {
  int gid = blockIdx.x * blockDim.x + threadIdx.x;
  int n = gid >> 6, lane = gid & 63;
  if (n >= N) return;
  int beg = ro[n], end = ro[n + 1];
  float ad = a_d[n];

  int g = lane >> 3, l3 = lane & 7;
  float sacc = 0.f;
  float accv[8] = {};
  if (g == 0) {   // self-loop
    float w = __expf(lrelu(a_s[n] + ad));
    sacc = w;
    const u16x8 hv = *(const u16x8*)&h2b[(size_t)n * OUT_D + l3 * 8];
    #pragma unroll
    for (int q = 0; q < 8; ++q) accv[q] = w * bf2f(hv[q]);
  }
  #pragma unroll 4
  for (int j = beg; j < end; j += 8) {
    int jj = j + g;
    bool valid = jj < end;
    int sidx = col[valid ? jj : beg];
    float w = __expf(lrelu(a_s[sidx] + ad));
    w = valid ? w : 0.f;
    sacc += w;
    const u16x8 hv = *(const u16x8*)&h2b[(size_t)sidx * OUT_D + l3 * 8];
    #pragma unroll
    for (int q = 0; q < 8; ++q) accv[q] += w * bf2f(hv[q]);
  }
  sacc += __shfl_xor(sacc, 8);
  sacc += __shfl_xor(sacc, 16);
  sacc += __shfl_xor(sacc, 32);
  float rcp = 1.f / sacc;
  #pragma unroll
  for (int q = 0; q < 8; ++q) {
    accv[q] *= rcp;
    accv[q] += __shfl_xor(accv[q], 8);
    accv[q] += __shfl_xor(accv[q], 16);
    accv[q] += __shfl_xor(accv[q], 32);
  }
  if (lane < 8) {
    float* op = out + (size_t)n * OUT_D + lane * 8;
    const float* bp = b2 + lane * 8;
    float4 o0 = {accv[0] + bp[0], accv[1] + bp[1], accv[2] + bp[2], accv[3] + bp[3]};
    float4 o1 = {accv[4] + bp[4], accv[5] + bp[5], accv[6] + bp[6], accv[7] + bp[7]};
    *(float4*)op = o0;
    *(float4*)(op + 4) = o1;
  }
}

extern "C" void kernel_launch(void* const* d_in, const int* in_sizes, int n_in,
                              void* d_out, int out_size, void* d_ws, size_t ws_size,
                              hipStream_t stream) {
  const float* x    = (const float*)d_in[0];
  const int*   ei   = (const int*)d_in[1];
  const float* W1   = (const float*)d_in[2];
  const float* as1w = (const float*)d_in[3];
  const float* ad1w = (const float*)d_in[4];
  const float* b1   = (const float*)d_in[5];
  const float* W2   = (const float*)d_in[6];
  const float* as2w = (const float*)d_in[7];
  const float* ad2w = (const float*)d_in[8];
  const float* b2   = (const float*)d_in[9];
  float* out = (float*)d_out;

  const int N   = in_sizes[0] / IN_D;
  const int E   = in_sizes[1] / 2;
  const int NSB = cdiv(N, 1024);   // super-buckets (dst>>10)

  // Workspace layout (element offsets in 4B units). ~110 MB.
  float* ws = (float*)d_ws;
  size_t off = 0;
  u16*   hb1  = (u16*)(ws + off); off += (size_t)N * IN_D / 2;   // bf16 h1
  u16*   h2b  = (u16*)(ws + off); off += (size_t)N * OUT_D / 2;  // bf16 h2
  float* a_s1 = ws + off; off += (size_t)N * 2;
  float* a_d1 = ws + off; off += (size_t)N * 2;
  float* a_s2 = ws + off; off += N;
  float* a_d2 = ws + off; off += N;
  int*   sbCount = (int*)(ws + off); off += 128;
  int2*  st1  = (int2*)(ws + off); off += (size_t)NSB * SBCAP * 2;  // staging
  int*   ro   = (int*)(ws + off); off += (size_t)N + 1;
  int*   col  = (int*)(ws + off); off += E;
  u16*   WThi = (u16*)(ws + off); off += (IN_D * IN_D) / 2;
  u16*   WTlo = (u16*)(ws + off); off += (IN_D * IN_D) / 2;
  u16*   W2Thi = (u16*)(ws + off); off += (HID * OUT_D) / 2;
  u16*   W2Tlo = (u16*)(ws + off); off += (HID * OUT_D) / 2;

  hipMemsetAsync(sbCount, 0, 128 * sizeof(int), stream);

  // Weight prep (gemm1 dependency; tiny)
  k_prep<<<cdiv(IN_D * IN_D + HID * OUT_D, 256), 256, 0, stream>>>(
      W1, WThi, WTlo, W2, W2Thi, W2Tlo);

  // Fused gemm1 || sort1 (independent chains overlap on the CUs)
  const int G1 = cdiv(N, 128);
  const int G2 = cdiv(E, 2048);
  k_gemm1sort<<<G1 + G2, 512, 0, stream>>>(x, WThi, WTlo, as1w, ad1w, hb1, a_s1, a_d1, N,
                                           ei, E, sbCount, st1, G1, G2);

  // Sort pass 2 -> flat CSR
  k_sort2<<<NSB, 256, 0, stream>>>(sbCount, st1, ro, col, N);

  // Layer-1 aggregation + Layer-2 GEMM fused
  k_fagg1g2<<<cdiv(N, 16), 256, 0, stream>>>(ro, col, a_s1, a_d1, hb1, b1,
                                             W2Thi, W2Tlo, as2w, ad2w, h2b, a_s2, a_d2, N);

  // Layer-2 aggregation + bias
  k_fagg2<<<cdiv((long long)N * 64, 256), 256, 0, stream>>>(ro, col, a_s2, a_d2, h2b, b2, out, N);
}

// Round 21
// 301.514 us; speedup vs baseline: 1.2252x; 1.2252x over previous
//
#include <hip/hip_runtime.h>
#include <hip/hip_bf16.h>
#include <cstdint>
#include <cstddef>

#define IN_D 256
#define HID 128
#define OUT_D 64
#define NSLOPE 0.2f
#define SBCAP 20480   // per-super-bucket staging capacity (mean 16.4k, +32 sigma)

typedef __attribute__((ext_vector_type(8))) short bf16x8;
typedef __attribute__((ext_vector_type(4))) float f32x4;
typedef __attribute__((ext_vector_type(8))) unsigned short u16x8;
typedef unsigned short u16;

static inline int cdiv(long long a, long long b) { return (int)((a + b - 1) / b); }

__device__ __forceinline__ float lrelu(float v) { return v >= 0.f ? v : NSLOPE * v; }
__device__ __forceinline__ int imin(int a, int b) { return a < b ? a : b; }

// f32 -> bf16 (RNE) via bit ops
__device__ __forceinline__ u16 f2bf(float f) {
  unsigned u = __float_as_uint(f);
  return (u16)((u + 0x7FFFu + ((u >> 16) & 1u)) >> 16);
}
__device__ __forceinline__ float bf2f(u16 h) {
  return __uint_as_float((unsigned)h << 16);
}

// ---------------- FUSED: weight prep || sort pass 1 -------------------------
// prep (minority rider, 288 blocks): W1/W2 -> transposed split-bf16.
// sort1 (782 blocks): 2048 edges -> super-buckets (dst>>10) via LDS hist,
// ONE returning global atomic per (block,bin), LDS-returning ranks.
__launch_bounds__(256)
__global__ void k_prepsort1(const float* __restrict__ W1, u16* __restrict__ WThi,
                            u16* __restrict__ WTlo, const float* __restrict__ W2,
                            u16* __restrict__ W2Thi, u16* __restrict__ W2Tlo,
                            const int* __restrict__ ei, int E,
                            int* __restrict__ sbCount, int2* __restrict__ st1,
                            int GP, int GS) {
  __shared__ int hist[128], gb[128], cur[128];
  int bid = blockIdx.x;
  int m2 = (GP < GS ? GP : GS) * 2;
  int type, tb;
  if (bid < m2) { type = bid & 1; tb = bid >> 1; }
  else { int ex = bid - m2; type = (GP > GS) ? 0 : 1; tb = m2 / 2 + ex; }
  int tid = threadIdx.x;

  if (type == 0) {
    // ---- prep ----
    int idx = tb * 256 + tid;
    if (idx < IN_D * IN_D) {
      int k = idx >> 8, n = idx & 255;
      float f = W1[idx];
      u16 h = f2bf(f);
      WThi[n * IN_D + k] = h;
      WTlo[n * IN_D + k] = f2bf(f - bf2f(h));
    }
    int idx2 = idx - IN_D * IN_D;
    if (idx2 >= 0 && idx2 < HID * OUT_D) {
      int k = idx2 >> 6, n = idx2 & 63;
      float f = W2[idx2];
      u16 h = f2bf(f);
      W2Thi[n * HID + k] = h;
      W2Tlo[n * HID + k] = f2bf(f - bf2f(h));
    }
    return;
  }

  // ---- sort1: 8 edges/thread (256 thr -> 2048 edges/block) ----
  if (tid < 128) hist[tid] = 0;
  __syncthreads();
  int base = tb * 2048 + tid;
  int sv[8], dv[8]; bool vv[8];
  #pragma unroll
  for (int q = 0; q < 8; ++q) {
    int i = base + q * 256;
    vv[q] = i < E;
    int ic = vv[q] ? i : 0;
    sv[q] = ei[ic];
    dv[q] = ei[E + ic];
  }
  #pragma unroll
  for (int q = 0; q < 8; ++q)
    if (vv[q]) atomicAdd(&hist[dv[q] >> 10], 1);   // LDS, non-returning
  __syncthreads();
  if (tid < 128) {
    int h = hist[tid];
    gb[tid] = h ? atomicAdd(&sbCount[tid], h) : 0; // ONE returning atomic/bin
    cur[tid] = 0;
  }
  __syncthreads();
  #pragma unroll
  for (int q = 0; q < 8; ++q)
    if (vv[q]) {
      int sb = dv[q] >> 10;
      int r = atomicAdd(&cur[sb], 1);              // LDS returning (fast)
      int slot = gb[sb] + r;
      if (slot < SBCAP) st1[(size_t)sb * SBCAP + slot] = make_int2(sv[q], dv[q]);
    }
}

// ---------------- FUSED: gemm1 || sort pass 2 -------------------------------
// gemm1 (782 blocks): BM=128, 8 waves, LDS-staged split-bf16 B (padded rows).
// sort2 (98 rider blocks, 512 thr): super-bucket -> per-node CSR; its 14.3KB
// of LDS overlays the gemm branch's 40KB buffer (no extra LDS).
__launch_bounds__(512)
__global__ void k_gemm1sort2(const float* __restrict__ x, const u16* __restrict__ WThi,
                             const u16* __restrict__ WTlo,
                             const float* __restrict__ as1, const float* __restrict__ ad1,
                             u16* __restrict__ hb, float* __restrict__ a_s,
                             float* __restrict__ a_d, int N,
                             const int* __restrict__ sbCount, const int2* __restrict__ st1,
                             int* __restrict__ ro, int* __restrict__ col,
                             int G1, int G2) {
  __shared__ u16 ldsb[2][10240];  // 40KB; sort2 overlays ints in ldsb[0]
  int bid = blockIdx.x;
  int m2 = (G1 < G2 ? G1 : G2) * 2;
  int type, tb;
  if (bid < m2) { type = bid & 1; tb = bid >> 1; }
  else { int ex = bid - m2; type = (G1 > G2) ? 0 : 1; tb = m2 / 2 + ex; }
  int tid = threadIdx.x;

  if (type == 1) {
    // ---- sort2 (512 threads): hist + scan + ranked scatter ----
    int* hist2 = (int*)&ldsb[0][0];      // [1024]
    int* pref  = hist2 + 1024;           // [1024]
    int* cur   = hist2 + 2048;           // [1024]
    int* sc    = hist2 + 3072;           // [512]
    int* gbc   = hist2 + 3584;           // [2] gbase, cnt
    int sb = tb;
    int nb0 = sb << 10;
    if (tid == 0) {
      int g = 0;
      for (int b = 0; b < sb; ++b) g += imin(sbCount[b], SBCAP);
      gbc[0] = g;
      gbc[1] = imin(sbCount[sb], SBCAP);
    }
    for (int t = tid; t < 1024; t += 512) hist2[t] = 0;
    __syncthreads();
    int gbase = gbc[0], cnt = gbc[1];
    const int2* sp = st1 + (size_t)sb * SBCAP;
    for (int j = tid; j < cnt; j += 512) atomicAdd(&hist2[sp[j].y - nb0], 1);
    __syncthreads();
    int a0 = hist2[tid * 2], a1 = hist2[tid * 2 + 1];
    int s2 = a0 + a1;
    sc[tid] = s2; __syncthreads();
    for (int o = 1; o < 512; o <<= 1) {
      int add = (tid >= o) ? sc[tid - o] : 0;
      __syncthreads();
      sc[tid] += add;
      __syncthreads();
    }
    int eb = sc[tid] - s2;
    pref[tid * 2] = eb;
    pref[tid * 2 + 1] = eb + a0;
    __syncthreads();
    for (int t = tid; t < 1024; t += 512) {
      cur[t] = pref[t];
      int n = nb0 + t;
      if (n < N) ro[n] = gbase + pref[t];
    }
    if (sb == G2 - 1 && tid == 0) ro[N] = gbase + cnt;
    __syncthreads();
    for (int j = tid; j < cnt; j += 512) {
      int2 e = sp[j];
      int r = atomicAdd(&cur[e.y - nb0], 1);       // LDS returning
      col[gbase + r] = e.x;                        // L2-resident span write
    }
    return;
  }

  // ---- gemm1 (split-bf16 MFMA, LDS-staged B) ----
  int w = tid >> 6, l = tid & 63;
  int l15 = l & 15, l4 = l >> 4;
  int rowbase = tb * 128 + w * 16;
  int row = rowbase + l15;
  int rowc = (row < N) ? row : (N - 1);
  const float* xp = x + (size_t)rowc * IN_D + l4 * 8;

  f32x4 acc[16];
  #pragma unroll
  for (int t = 0; t < 16; ++t) acc[t] = (f32x4){0.f, 0.f, 0.f, 0.f};

  const int ridx = (l15 * 5 + l4) * 8;   // padded rows: + t*640 per tile

  for (int kk = 0; kk < 8; ++kk) {
    __syncthreads();
    #pragma unroll
    for (int it = 0; it < 2; ++it) {
      int c = tid + it * 512;
      int n = c >> 2, ch = c & 3;
      size_t soff = (size_t)n * IN_D + kk * 32 + ch * 8;
      uint4 vh = *(const uint4*)(WThi + soff);
      uint4 vl = *(const uint4*)(WTlo + soff);
      int dsl = (n * 5 + ch) * 8;
      *(uint4*)&ldsb[0][dsl] = vh;
      *(uint4*)&ldsb[1][dsl] = vl;
    }
    __syncthreads();

    f32x4 v0 = *(const f32x4*)(xp + kk * 32);
    f32x4 v1 = *(const f32x4*)(xp + kk * 32 + 4);
    bf16x8 ah, al;
    #pragma unroll
    for (int j = 0; j < 4; ++j) {
      u16 h0 = f2bf(v0[j]);
      ah[j] = (short)h0; al[j] = (short)f2bf(v0[j] - bf2f(h0));
      u16 h1 = f2bf(v1[j]);
      ah[j + 4] = (short)h1; al[j + 4] = (short)f2bf(v1[j] - bf2f(h1));
    }
    #pragma unroll
    for (int t = 0; t < 16; ++t) {
      bf16x8 bh = *(const bf16x8*)&ldsb[0][ridx + t * 640];
      bf16x8 bl = *(const bf16x8*)&ldsb[1][ridx + t * 640];
      acc[t] = __builtin_amdgcn_mfma_f32_16x16x32_bf16(ah, bh, acc[t], 0, 0, 0);
      acc[t] = __builtin_amdgcn_mfma_f32_16x16x32_bf16(al, bh, acc[t], 0, 0, 0);
      acc[t] = __builtin_amdgcn_mfma_f32_16x16x32_bf16(ah, bl, acc[t], 0, 0, 0);
    }
  }

  #pragma unroll
  for (int r = 0; r < 4; ++r) {
    int rr = rowbase + l4 * 4 + r;
    if (rr < N) {
      u16* hp = hb + (size_t)rr * IN_D + l15;
      #pragma unroll
      for (int t = 0; t < 16; ++t) hp[t * 16] = f2bf(acc[t][r]);
    }
  }
  float asv[16], adv[16];
  #pragma unroll
  for (int t = 0; t < 16; ++t) { asv[t] = as1[t * 16 + l15]; adv[t] = ad1[t * 16 + l15]; }
  float ps0[4] = {}, ps1[4] = {}, pd0[4] = {}, pd1[4] = {};
  #pragma unroll
  for (int t = 0; t < 16; ++t) {
    #pragma unroll
    for (int r = 0; r < 4; ++r) {
      float v = acc[t][r];
      if (t < 8) { ps0[r] += v * asv[t]; pd0[r] += v * adv[t]; }
      else       { ps1[r] += v * asv[t]; pd1[r] += v * adv[t]; }
    }
  }
  #pragma unroll
  for (int r = 0; r < 4; ++r) {
    #pragma unroll
    for (int o = 1; o < 16; o <<= 1) {
      ps0[r] += __shfl_xor(ps0[r], o); ps1[r] += __shfl_xor(ps1[r], o);
      pd0[r] += __shfl_xor(pd0[r], o); pd1[r] += __shfl_xor(pd1[r], o);
    }
    int rr = rowbase + l4 * 4 + r;
    if (l15 == 0 && rr < N) {
      a_s[rr * 2] = ps0[r]; a_s[rr * 2 + 1] = ps1[r];
      a_d[rr * 2] = pd0[r]; a_d[rr * 2 + 1] = pd1[r];
    }
  }
}

// ---------------- Layer 1 agg + Layer 2 GEMM, fused (flat CSR) --------------
__launch_bounds__(256)
__global__ void k_fagg1g2(const int* __restrict__ ro, const int* __restrict__ col,
                          const float* __restrict__ a_s, const float* __restrict__ a_d,
                          const u16* __restrict__ hb, const float* __restrict__ b1,
                          const u16* __restrict__ W2Thi, const u16* __restrict__ W2Tlo,
                          const float* __restrict__ as2, const float* __restrict__ ad2,
                          u16* __restrict__ h2b, float* __restrict__ a_s2,
                          float* __restrict__ a_d2, int N) {
  __shared__ float rowLds[16][132];
  __shared__ float red[2][16][4];
  int tid = threadIdx.x;
  int wid = tid >> 6, lane = tid & 63;
  int base = blockIdx.x * 16;

  int half = lane >> 5;
  int l5 = lane & 31;
  int head = l5 >> 4;

  for (int rr = 0; rr < 4; ++rr) {
    int ln = wid * 4 + rr;
    int n = base + ln;
    if (n >= N) { if (lane < 16) for (int q = 0; q < 8; ++q) rowLds[ln][lane * 8 + q] = 0.f; continue; }
    int beg = ro[n], end = ro[n + 1];
    float ad0 = a_d[2 * n], ad1 = a_d[2 * n + 1];
    float myAd = head ? ad1 : ad0;

    float sacc = 0.f;
    float accv[8] = {};
    if (half == 0) {   // self-loop
      float2 asn = *(const float2*)&a_s[2 * (size_t)n];
      float wv = __expf(lrelu((head ? asn.y : asn.x) + myAd));
      sacc = wv;
      const u16x8 hv = *(const u16x8*)&hb[(size_t)n * IN_D + l5 * 8];
      #pragma unroll
      for (int q = 0; q < 8; ++q) accv[q] = wv * bf2f(hv[q]);
    }
    #pragma unroll 4
    for (int j = beg; j < end; j += 2) {
      int jj = j + half;
      bool valid = jj < end;
      int sidx = col[valid ? jj : beg];
      float2 asv = *(const float2*)&a_s[2 * (size_t)sidx];
      float e = (head ? asv.y : asv.x) + myAd;
      float wv = __expf(lrelu(e));
      wv = valid ? wv : 0.f;
      sacc += wv;
      const u16x8 hv = *(const u16x8*)&hb[(size_t)sidx * IN_D + l5 * 8];
      #pragma unroll
      for (int q = 0; q < 8; ++q) accv[q] += wv * bf2f(hv[q]);
    }
    sacc += __shfl_xor(sacc, 32);
    float myScale = 0.5f / sacc;
    #pragma unroll
    for (int q = 0; q < 8; ++q) {
      accv[q] *= myScale;
      accv[q] += __shfl_xor(accv[q], 16);
      accv[q] += __shfl_xor(accv[q], 32);
    }
    if (lane < 16) {
      #pragma unroll
      for (int q = 0; q < 8; ++q) rowLds[ln][lane * 8 + q] = accv[q];
    }
  }
  __syncthreads();

  int l15 = lane & 15, l4 = lane >> 4;
  f32x4 acc2 = (f32x4){0.f, 0.f, 0.f, 0.f};
  #pragma unroll
  for (int kk = 0; kk < 4; ++kk) {
    int k0 = kk * 32 + l4 * 8;
    f32x4 bv0 = *(const f32x4*)(b1 + k0);
    f32x4 bv1 = *(const f32x4*)(b1 + k0 + 4);
    bf16x8 ah, al;
    #pragma unroll
    for (int j = 0; j < 4; ++j) {
      float u0 = rowLds[l15][k0 + j] + bv0[j]; u0 = (u0 > 0.f) ? u0 : 0.f;
      u16 h0 = f2bf(u0);
      ah[j] = (short)h0; al[j] = (short)f2bf(u0 - bf2f(h0));
      float u1 = rowLds[l15][k0 + 4 + j] + bv1[j]; u1 = (u1 > 0.f) ? u1 : 0.f;
      u16 h1 = f2bf(u1);
      ah[j + 4] = (short)h1; al[j + 4] = (short)f2bf(u1 - bf2f(h1));
    }
    size_t boff = (size_t)(wid * 16 + l15) * HID + k0;
    bf16x8 bh = *(const bf16x8*)(W2Thi + boff);
    bf16x8 bl = *(const bf16x8*)(W2Tlo + boff);
    acc2 = __builtin_amdgcn_mfma_f32_16x16x32_bf16(ah, bh, acc2, 0, 0, 0);
    acc2 = __builtin_amdgcn_mfma_f32_16x16x32_bf16(al, bh, acc2, 0, 0, 0);
    acc2 = __builtin_amdgcn_mfma_f32_16x16x32_bf16(ah, bl, acc2, 0, 0, 0);
  }

  float asv = as2[wid * 16 + l15], adv = ad2[wid * 16 + l15];
  float ps[4], pd[4];
  #pragma unroll
  for (int r = 0; r < 4; ++r) {
    int n = base + l4 * 4 + r;
    if (n < N) h2b[(size_t)n * OUT_D + wid * 16 + l15] = f2bf(acc2[r]);
    ps[r] = acc2[r] * asv; pd[r] = acc2[r] * adv;
    #pragma unroll
    for (int o = 1; o < 16; o <<= 1) { ps[r] += __shfl_xor(ps[r], o); pd[r] += __shfl_xor(pd[r], o); }
    if (l15 == 0) { red[0][l4 * 4 + r][wid] = ps[r]; red[1][l4 * 4 + r][wid] = pd[r]; }
  }
  __syncthreads();
  if (tid < 32) {
    int ln = tid >> 1, kind = tid & 1;
    int n = base + ln;
    if (n < N) {
      float v = red[kind][ln][0] + red[kind][ln][1] + red[kind][ln][2] + red[kind][ln][3];
      if (kind == 0) a_s2[n] = v; else a_d2[n] = v;
    }
  }
}

// ---------------- Layer 2: single-pass edge pipeline + bias (flat CSR) ------
__launch_bounds__(256)
__global__ void k_fagg2(const int* __restrict__ ro, const int* __restrict__ col,
                        const float* __restrict__ a_s, const float* __restrict__ a_d,
                        const u16* __restrict__ h2b, const float* __restrict__ b2,
                        float* __restrict__ out, int N) {
  int gid = blockIdx.x * blockDim.x + threadIdx.x;
  int n = gid >> 6, lane = gid & 63;
  if (n >= N) return;
  int beg = ro[n], end = ro[n + 1];
  float ad = a_d[n];

  int g = lane >> 3, l3 = lane & 7;
  float sacc = 0.f;
  float accv[8] = {};
  if (g == 0) {   // self-loop
    float w = __expf(lrelu(a_s[n] + ad));
    sacc = w;
    const u16x8 hv = *(const u16x8*)&h2b[(size_t)n * OUT_D + l3 * 8];
    #pragma unroll
    for (int q = 0; q < 8; ++q) accv[q] = w * bf2f(hv[q]);
  }
  #pragma unroll 4
  for (int j = beg; j < end; j += 8) {
    int jj = j + g;
    bool valid = jj < end;
    int sidx = col[valid ? jj : beg];
    float w = __expf(lrelu(a_s[sidx] + ad));
    w = valid ? w : 0.f;
    sacc += w;
    const u16x8 hv = *(const u16x8*)&h2b[(size_t)sidx * OUT_D + l3 * 8];
    #pragma unroll
    for (int q = 0; q < 8; ++q) accv[q] += w * bf2f(hv[q]);
  }
  sacc += __shfl_xor(sacc, 8);
  sacc += __shfl_xor(sacc, 16);
  sacc += __shfl_xor(sacc, 32);
  float rcp = 1.f / sacc;
  #pragma unroll
  for (int q = 0; q < 8; ++q) {
    accv[q] *= rcp;
    accv[q] += __shfl_xor(accv[q], 8);
    accv[q] += __shfl_xor(accv[q], 16);
    accv[q] += __shfl_xor(accv[q], 32);
  }
  if (lane < 8) {
    float* op = out + (size_t)n * OUT_D + lane * 8;
    const float* bp = b2 + lane * 8;
    float4 o0 = {accv[0] + bp[0], accv[1] + bp[1], accv[2] + bp[2], accv[3] + bp[3]};
    float4 o1 = {accv[4] + bp[4], accv[5] + bp[5], accv[6] + bp[6], accv[7] + bp[7]};
    *(float4*)op = o0;
    *(float4*)(op + 4) = o1;
  }
}

extern "C" void kernel_launch(void* const* d_in, const int* in_sizes, int n_in,
                              void* d_out, int out_size, void* d_ws, size_t ws_size,
                              hipStream_t stream) {
  const float* x    = (const float*)d_in[0];
  const int*   ei   = (const int*)d_in[1];
  const float* W1   = (const float*)d_in[2];
  const float* as1w = (const float*)d_in[3];
  const float* ad1w = (const float*)d_in[4];
  const float* b1   = (const float*)d_in[5];
  const float* W2   = (const float*)d_in[6];
  const float* as2w = (const float*)d_in[7];
  const float* ad2w = (const float*)d_in[8];
  const float* b2   = (const float*)d_in[9];
  float* out = (float*)d_out;

  const int N   = in_sizes[0] / IN_D;
  const int E   = in_sizes[1] / 2;
  const int NSB = cdiv(N, 1024);   // super-buckets (dst>>10)

  // Workspace layout (element offsets in 4B units). ~110 MB.
  float* ws = (float*)d_ws;
  size_t off = 0;
  u16*   hb1  = (u16*)(ws + off); off += (size_t)N * IN_D / 2;   // bf16 h1
  u16*   h2b  = (u16*)(ws + off); off += (size_t)N * OUT_D / 2;  // bf16 h2
  float* a_s1 = ws + off; off += (size_t)N * 2;
  float* a_d1 = ws + off; off += (size_t)N * 2;
  float* a_s2 = ws + off; off += N;
  float* a_d2 = ws + off; off += N;
  int*   sbCount = (int*)(ws + off); off += 128;
  int2*  st1  = (int2*)(ws + off); off += (size_t)NSB * SBCAP * 2;  // staging
  int*   ro   = (int*)(ws + off); off += (size_t)N + 1;
  int*   col  = (int*)(ws + off); off += E;
  u16*   WThi = (u16*)(ws + off); off += (IN_D * IN_D) / 2;
  u16*   WTlo = (u16*)(ws + off); off += (IN_D * IN_D) / 2;
  u16*   W2Thi = (u16*)(ws + off); off += (HID * OUT_D) / 2;
  u16*   W2Tlo = (u16*)(ws + off); off += (HID * OUT_D) / 2;

  hipMemsetAsync(sbCount, 0, 128 * sizeof(int), stream);

  // Launch A: prep || sort1 (both 256-thread, independent)
  const int GP = cdiv(IN_D * IN_D + HID * OUT_D, 256);
  const int GS = cdiv(E, 2048);
  k_prepsort1<<<GP + GS, 256, 0, stream>>>(W1, WThi, WTlo, W2, W2Thi, W2Tlo,
                                           ei, E, sbCount, st1, GP, GS);

  // Launch B: gemm1 || sort2 (sort2 = minority rider, LDS overlaid)
  const int G1 = cdiv(N, 128);
  k_gemm1sort2<<<G1 + NSB, 512, 0, stream>>>(x, WThi, WTlo, as1w, ad1w, hb1, a_s1, a_d1, N,
                                             sbCount, st1, ro, col, G1, NSB);

  // Layer-1 aggregation + Layer-2 GEMM fused
  k_fagg1g2<<<cdiv(N, 16), 256, 0, stream>>>(ro, col, a_s1, a_d1, hb1, b1,
                                             W2Thi, W2Tlo, as2w, ad2w, h2b, a_s2, a_d2, N);

  // Layer-2 aggregation + bias
  k_fagg2<<<cdiv((long long)N * 64, 256), 256, 0, stream>>>(ro, col, a_s2, a_d2, h2b, b2, out, N);
}